// Round 2
// baseline (16191.707 us; speedup 1.0000x reference)
//
#include <hip/hip_runtime.h>

#define T_STEPS 2048
#define H       500
#define E       300
#define HP      512      // padded h stride
#define G       63       // blocks per layer (4 waves each, 2 units/wave)
#define WPB     4
#define NT      256
#define NWAVES  250      // active waves per layer (250 * 2 units = 500)
#define NCLS    20
#define BIAS2   2.0f

__device__ __forceinline__ float sigm_(float x){ return 1.0f/(1.0f+__expf(-x)); }
__device__ __forceinline__ float tanh_(float x){ return 2.0f/(1.0f+__expf(-2.0f*x)) - 1.0f; }

// h buffers are t-indexed; value 0 == "not yet written" (real values are h+2 in (1,3)).
__global__ __launch_bounds__(256) void lstm_init(float* hs) {
    int i = blockIdx.x*256 + threadIdx.x;            // one float4 per thread
    const int NH4 = (T_STEPS+1)*HP/4;                // 262272 float4 per layer buffer
    float4 z  = make_float4(0.f,0.f,0.f,0.f);
    float4 b2 = make_float4(BIAS2,BIAS2,BIAS2,BIAS2);
    bool seed = (i < H/4) || (i >= NH4 && i < NH4 + H/4);   // t=0 state: h=0 -> stored 2.0
    ((float4*)hs)[i] = seed ? b2 : z;
}

// One wave owns units {2*wg, 2*wg+1}: 8 gate rows x 1024 padded cols in VGPRs.
// Col layout L0: [0,320)=x(real 300), [320,820)=h(t-1), rest pad.
// Col layout L1: [0,512)=h0(t) (real 500), [512,1012)=h1(t-1), rest pad.
template<int LAYER>
__device__ __forceinline__ void lstm_layer(
    const int* __restrict__ seq, const float* __restrict__ emb,
    const float* __restrict__ Wih, const float* __restrict__ Whh,
    const float* __restrict__ bih, const float* __restrict__ bhh,
    float* hprev, float* hown, int wg)
{
    const int j = (int)(threadIdx.x & 63);
    const int unit0 = 2*wg;

    // ---- weights -> registers (one-time) ----
    float4 w[8][4];
    float  bsum[8];
    #pragma unroll
    for (int r = 0; r < 8; ++r) {
        const int lu = r >> 2, gate = r & 3;        // r = lu*4 + gate (unit-major)
        const int Rg = gate*H + unit0 + lu;         // PyTorch gate-major global row
        bsum[r] = bih[Rg] + bhh[Rg];
        #pragma unroll
        for (int k = 0; k < 4; ++k) {
            const int c = 16*j + 4*k;
            float4 val = make_float4(0.f,0.f,0.f,0.f);
            if (LAYER == 0) {
                if (c + 4 <= E)                     val = *(const float4*)&Wih[(size_t)Rg*E + c];
                else if (c >= 320 && c + 4 <= 820)  val = *(const float4*)&Whh[(size_t)Rg*H + (c-320)];
            } else {
                if (c + 4 <= H)                     val = *(const float4*)&Wih[(size_t)Rg*H + c];
                else if (c >= 512 && c + 4 <= 1012) val = *(const float4*)&Whh[(size_t)Rg*H + (c-512)];
            }
            w[r][k] = val;
        }
    }

    float cs0 = 0.f, cs1 = 0.f;

    for (int t = 1; t <= T_STEPS; ++t) {
        float inp[16];
        #pragma unroll
        for (int i = 0; i < 16; ++i) inp[i] = 0.f;

        // L0: issue x loads before the poll (latency hides under the wait)
        if (LAYER == 0) {
            const int erow = seq[t-1];
            #pragma unroll
            for (int k = 0; k < 4; ++k) {
                const int c = 16*j + 4*k;
                if (c + 4 <= E) {
                    float4 xv = *(const float4*)&emb[(size_t)erow*E + c];
                    inp[4*k+0]=xv.x; inp[4*k+1]=xv.y; inp[4*k+2]=xv.z; inp[4*k+3]=xv.w;
                }
            }
        }

        // per-chunk poll sources
        const float* p[4]; bool v[4];
        #pragma unroll
        for (int k = 0; k < 4; ++k) {
            const int c = 16*j + 4*k;
            if (LAYER == 0) {
                v[k] = (c >= 320) && (c + 4 <= 820);
                p[k] = hown + (size_t)(t-1)*HP + (c - 320);
            } else {
                if (c < 512) { v[k] = (c + 4 <= H);    p[k] = hprev + (size_t)t*HP + c; }
                else         { v[k] = (c + 4 <= 1012); p[k] = hown + (size_t)(t-1)*HP + (c-512); }
            }
        }

        // spin on the data itself: nonzero == published (stored value = h + 2)
        bool done;
        do {
            done = true;
            #pragma unroll
            for (int k = 0; k < 4; ++k) {
                if (v[k]) {
                    float f0 = __hip_atomic_load(p[k]+0, __ATOMIC_RELAXED, __HIP_MEMORY_SCOPE_AGENT);
                    float f1 = __hip_atomic_load(p[k]+1, __ATOMIC_RELAXED, __HIP_MEMORY_SCOPE_AGENT);
                    float f2 = __hip_atomic_load(p[k]+2, __ATOMIC_RELAXED, __HIP_MEMORY_SCOPE_AGENT);
                    float f3 = __hip_atomic_load(p[k]+3, __ATOMIC_RELAXED, __HIP_MEMORY_SCOPE_AGENT);
                    done = done && (f0!=0.f) && (f1!=0.f) && (f2!=0.f) && (f3!=0.f);
                    inp[4*k+0]=f0-BIAS2; inp[4*k+1]=f1-BIAS2; inp[4*k+2]=f2-BIAS2; inp[4*k+3]=f3-BIAS2;
                }
            }
        } while (!__all((int)done));

        // matvec: 8 rows x 16 cols per lane, weights in regs
        float acc[8];
        #pragma unroll
        for (int r = 0; r < 8; ++r) acc[r] = 0.f;
        #pragma unroll
        for (int r = 0; r < 8; ++r) {
            #pragma unroll
            for (int k = 0; k < 4; ++k) {
                acc[r] += w[r][k].x*inp[4*k+0] + w[r][k].y*inp[4*k+1]
                        + w[r][k].z*inp[4*k+2] + w[r][k].w*inp[4*k+3];
            }
        }
        // full-wave butterfly: every lane ends with row totals
        #pragma unroll
        for (int m = 32; m >= 1; m >>= 1) {
            #pragma unroll
            for (int r = 0; r < 8; ++r) acc[r] += __shfl_xor(acc[r], m, 64);
        }
        #pragma unroll
        for (int r = 0; r < 8; ++r) acc[r] += bsum[r];

        // gates (uniform across lanes; c-state kept redundantly)
        float i0 = sigm_(acc[0]), f0 = sigm_(acc[1]), g0 = tanh_(acc[2]), o0 = sigm_(acc[3]);
        cs0 = f0*cs0 + i0*g0;
        float h0v = o0 * tanh_(cs0);
        float i1 = sigm_(acc[4]), f1 = sigm_(acc[5]), g1 = tanh_(acc[6]), o1 = sigm_(acc[7]);
        cs1 = f1*cs1 + i1*g1;
        float h1v = o1 * tanh_(cs1);

        if (j == 0) {
            float* dst = hown + (size_t)t*HP + unit0;
            __hip_atomic_store(dst+0, h0v + BIAS2, __ATOMIC_RELAXED, __HIP_MEMORY_SCOPE_AGENT);
            __hip_atomic_store(dst+1, h1v + BIAS2, __ATOMIC_RELAXED, __HIP_MEMORY_SCOPE_AGENT);
        }
    }
}

__launch_bounds__(NT)
__global__ void lstm_main(
    const int* __restrict__ seq, const float* __restrict__ emb,
    const float* __restrict__ Wih0, const float* __restrict__ Whh0,
    const float* __restrict__ bih0, const float* __restrict__ bhh0,
    const float* __restrict__ Wih1, const float* __restrict__ Whh1,
    const float* __restrict__ bih1, const float* __restrict__ bhh1,
    const float* __restrict__ fcW, const float* __restrict__ fcb,
    float* __restrict__ out,
    float* h0s, float* h1s)
{
    const int blk = blockIdx.x;
    const int wid = threadIdx.x >> 6;
    const int wg  = (blk % G)*WPB + wid;

    __shared__ float hfin[HP];

    if (blk < G) {
        if (wg < NWAVES)
            lstm_layer<0>(seq, emb, Wih0, Whh0, bih0, bhh0, nullptr, h0s, wg);
    } else {
        if (wg < NWAVES)
            lstm_layer<1>(nullptr, nullptr, Wih1, Whh1, bih1, bhh1, h0s, h1s, wg);

        if (blk == G) {
            // final FC on h1[T]
            const int tid = threadIdx.x;
            if (tid < 64) {
                #pragma unroll
                for (int i = 0; i < 8; ++i) {
                    int idx = tid*8 + i;
                    if (idx < H) {
                        float val;
                        do {
                            val = __hip_atomic_load(&h1s[(size_t)T_STEPS*HP + idx],
                                                    __ATOMIC_RELAXED, __HIP_MEMORY_SCOPE_AGENT);
                        } while (val == 0.f);
                        hfin[idx] = val - BIAS2;
                    }
                }
            }
            __syncthreads();
            if (tid < NCLS) {
                float acc = fcb[tid];
                for (int k = 0; k < H/4; ++k) {
                    float4 wv = *(const float4*)&fcW[(size_t)tid*H + 4*k];
                    acc += wv.x*hfin[4*k+0] + wv.y*hfin[4*k+1]
                         + wv.z*hfin[4*k+2] + wv.w*hfin[4*k+3];
                }
                out[tid] = acc;
            }
        }
    }
}

extern "C" void kernel_launch(void* const* d_in, const int* in_sizes, int n_in,
                              void* d_out, int out_size, void* d_ws, size_t ws_size,
                              hipStream_t stream)
{
    const int*   seq  = (const int*)d_in[0];
    const float* emb  = (const float*)d_in[1];
    const float* Wih0 = (const float*)d_in[2];
    const float* Whh0 = (const float*)d_in[3];
    const float* bih0 = (const float*)d_in[4];
    const float* bhh0 = (const float*)d_in[5];
    const float* Wih1 = (const float*)d_in[6];
    const float* Whh1 = (const float*)d_in[7];
    const float* bih1 = (const float*)d_in[8];
    const float* bhh1 = (const float*)d_in[9];
    const float* fcW  = (const float*)d_in[10];
    const float* fcb  = (const float*)d_in[11];
    float* out = (float*)d_out;

    float* h0s = (float*)d_ws;
    float* h1s = h0s + (size_t)(T_STEPS+1)*HP;

    // 2 * 2049 * 512 floats = 524544 float4 = 2049 blocks * 256 threads
    hipLaunchKernelGGL(lstm_init, dim3(2049), dim3(256), 0, stream, h0s);
    hipLaunchKernelGGL(lstm_main, dim3(2*G), dim3(NT), 0, stream,
                       seq, emb, Wih0, Whh0, bih0, bhh0, Wih1, Whh1, bih1, bhh1,
                       fcW, fcb, out, h0s, h1s);
}

// Round 4
// 11684.078 us; speedup vs baseline: 1.3858x; 1.3858x over previous
//
#include <hip/hip_runtime.h>

#define T_STEPS 2048
#define H       500
#define E       300
#define HP      512      // padded h stride (floats)
#define NCLS    20
#define NW      125      // waves (blocks) per layer, 4 units each
#define BIAS2   2.0f

typedef float v4f __attribute__((ext_vector_type(4)));

__device__ __forceinline__ float sigm_(float x){ return 1.0f/(1.0f+__expf(-x)); }
__device__ __forceinline__ float tanh_(float x){ return 2.0f/(1.0f+__expf(-2.0f*x)) - 1.0f; }

__device__ __forceinline__ v4f v4z() { v4f r; r.x=0.f; r.y=0.f; r.z=0.f; r.w=0.f; return r; }
__device__ __forceinline__ v4f v4sub(v4f v, float s){ v4f r; r.x=v.x-s; r.y=v.y-s; r.z=v.z-s; r.w=v.w-s; return r; }
__device__ __forceinline__ bool nz4(v4f v){ return v.x!=0.f && v.y!=0.f && v.z!=0.f && v.w!=0.f; }
__device__ __forceinline__ float dot4(v4f w, v4f x){ return w.x*x.x + w.y*x.y + w.z*x.z + w.w*x.w; }

// coalesced device-coherent (LLC) loads: bypass L1/L2 so cross-XCD stores are seen
__device__ __forceinline__ void poll2(const float* p0, const float* p1, v4f& a, v4f& b) {
    asm volatile("global_load_dwordx4 %0, %2, off sc0 sc1\n\t"
                 "global_load_dwordx4 %1, %3, off sc0 sc1\n\t"
                 "s_waitcnt vmcnt(0)"
                 : "=&v"(a), "=&v"(b)
                 : "v"(p0), "v"(p1)
                 : "memory");
}
__device__ __forceinline__ void poll4(const float* p0, const float* p1,
                                      const float* p2, const float* p3,
                                      v4f& a, v4f& b, v4f& c, v4f& d) {
    asm volatile("global_load_dwordx4 %0, %4, off sc0 sc1\n\t"
                 "global_load_dwordx4 %1, %5, off sc0 sc1\n\t"
                 "global_load_dwordx4 %2, %6, off sc0 sc1\n\t"
                 "global_load_dwordx4 %3, %7, off sc0 sc1\n\t"
                 "s_waitcnt vmcnt(0)"
                 : "=&v"(a), "=&v"(b), "=&v"(c), "=&v"(d)
                 : "v"(p0), "v"(p1), "v"(p2), "v"(p3)
                 : "memory");
}
__device__ __forceinline__ void store4_cc(float* p, v4f v) {
    asm volatile("global_store_dwordx4 %0, %1, off sc0 sc1"
                 :: "v"(p), "v"(v) : "memory");
}

// h buffers t-indexed; 0 == not yet written (real values are h+2 in (1,3)).
__global__ __launch_bounds__(256) void lstm_init(float* hs) {
    int i = blockIdx.x*256 + threadIdx.x;            // one v4f per thread
    const int NH4 = (T_STEPS+1)*HP/4;                // per-layer buffer in float4
    v4f b2; b2.x=BIAS2; b2.y=BIAS2; b2.z=BIAS2; b2.w=BIAS2;
    bool seed = (i < H/4) || (i >= NH4 && i < NH4 + H/4);   // t=0: h=0 -> stored 2.0
    ((v4f*)hs)[i] = seed ? b2 : v4z();
}

// One wave owns 4 hidden units (16 gate rows). Per-lane cols: two float4 chunks
// per 512-wide region: cols {4j..4j+4} and {256+4j..256+4j+4}.
// L0 regions: x (real 300) | h(t-1). L1 regions: h0(t) | h1(t-1).
template<int LAYER>
__device__ __forceinline__ void run_layer(
    const int* __restrict__ seq, const float* __restrict__ emb,
    const float* __restrict__ Wih, const float* __restrict__ Whh,
    const float* __restrict__ bih, const float* __restrict__ bhh,
    const float* hprev, float* hown, int wg)
{
    const int j  = (int)(threadIdx.x & 63);
    const int u0 = 4*wg;
    const int DIN = (LAYER==0) ? E : H;
    const int c0 = 4*j, c1 = 256 + 4*j;
    const bool hi = (c1 + 4 <= H);                   // j <= 60: chunk-1 cols are real

    // ---- weights + bias -> registers (one-time) ----
    v4f   w[16][4];
    float bs[16];
    #pragma unroll
    for (int r = 0; r < 16; ++r) {
        const int gate = r & 3, u = r >> 2;          // r = u*4 + gate
        const int Rg = gate*H + u0 + u;              // PyTorch gate-major row
        bs[r] = bih[Rg] + bhh[Rg];
        const float* wi = Wih + (size_t)Rg*DIN;
        const float* wh = Whh + (size_t)Rg*H;
        w[r][0] = (c0 + 4 <= DIN) ? *(const v4f*)(wi + c0) : v4z();
        w[r][1] = (c1 + 4 <= DIN) ? *(const v4f*)(wi + c1) : v4z();
        w[r][2] = *(const v4f*)(wh + c0);            // c0+4 <= 256 < 500, always real
        w[r][3] = hi ? *(const v4f*)(wh + c1) : v4z();
    }

    float cs[4] = {0.f, 0.f, 0.f, 0.f};

    for (int t = 1; t <= T_STEPS; ++t) {
        v4f i0, i1, i2, i3;

        if (LAYER == 0) {
            const int erow = seq[t-1];               // uniform
            const float* xr = emb + (size_t)erow*E;
            v4f xa = *(const v4f*)(xr + c0);         // c0+4 <= 256 < 300, always real
            v4f xb = v4z();
            if (c1 + 4 <= E) xb = *(const v4f*)(xr + c1);   // j <= 10
            const float* hp = hown + (size_t)(t-1)*HP;
            v4f ha, hb;
            for (;;) {
                poll2(hp + c0, hp + c1, ha, hb);
                bool ok = nz4(ha) && (!hi || nz4(hb));
                if (__all(ok)) break;
            }
            i0 = xa; i1 = xb;
            i2 = v4sub(ha, BIAS2);
            i3 = hi ? v4sub(hb, BIAS2) : v4z();
        } else {
            const float* pa = hprev + (size_t)t*HP;      // h0(t)
            const float* pb = hown  + (size_t)(t-1)*HP;  // h1(t-1)
            v4f a0, a1, b0, b1;
            for (;;) {
                poll4(pa + c0, pa + c1, pb + c0, pb + c1, a0, a1, b0, b1);
                bool ok = nz4(a0) && nz4(b0) && (!hi || (nz4(a1) && nz4(b1)));
                if (__all(ok)) break;
            }
            i0 = v4sub(a0, BIAS2);
            i1 = hi ? v4sub(a1, BIAS2) : v4z();
            i2 = v4sub(b0, BIAS2);
            i3 = hi ? v4sub(b1, BIAS2) : v4z();
        }

        // matvec: 16 rows x 16 cols/lane, weights resident in VGPRs
        float acc[16];
        #pragma unroll
        for (int r = 0; r < 16; ++r)
            acc[r] = dot4(w[r][0], i0) + dot4(w[r][1], i1)
                   + dot4(w[r][2], i2) + dot4(w[r][3], i3);
        #pragma unroll
        for (int m = 32; m >= 1; m >>= 1) {
            #pragma unroll
            for (int r = 0; r < 16; ++r) acc[r] += __shfl_xor(acc[r], m, 64);
        }

        // gates (uniform across lanes)
        float hv[4];
        #pragma unroll
        for (int u = 0; u < 4; ++u) {
            float gi = sigm_(acc[4*u+0] + bs[4*u+0]);
            float gf = sigm_(acc[4*u+1] + bs[4*u+1]);
            float gg = tanh_(acc[4*u+2] + bs[4*u+2]);
            float go = sigm_(acc[4*u+3] + bs[4*u+3]);
            cs[u] = gf*cs[u] + gi*gg;
            hv[u] = go * tanh_(cs[u]);
        }

        if (j == 0) {
            v4f hvv; hvv.x = hv[0]+BIAS2; hvv.y = hv[1]+BIAS2; hvv.z = hv[2]+BIAS2; hvv.w = hv[3]+BIAS2;
            store4_cc(hown + (size_t)t*HP + u0, hvv);
        }
    }
}

__launch_bounds__(64, 1)
__global__ void lstm_main(
    const int* __restrict__ seq, const float* __restrict__ emb,
    const float* __restrict__ Wih0, const float* __restrict__ Whh0,
    const float* __restrict__ bih0, const float* __restrict__ bhh0,
    const float* __restrict__ Wih1, const float* __restrict__ Whh1,
    const float* __restrict__ bih1, const float* __restrict__ bhh1,
    const float* __restrict__ fcW, const float* __restrict__ fcb,
    float* __restrict__ out,
    float* h0s, float* h1s)
{
    const int blk = blockIdx.x;
    const int j = (int)(threadIdx.x & 63);
    const int c0 = 4*j, c1 = 256 + 4*j;

    if (blk < NW) {
        run_layer<0>(seq, emb, Wih0, Whh0, bih0, bhh0, nullptr, h0s, blk);
    } else {
        const int wg = blk - NW;
        run_layer<1>(nullptr, nullptr, Wih1, Whh1, bih1, bhh1, h0s, h1s, wg);

        if (wg == 0) {
            // final FC on h1[T] (poll: other waves finish near-simultaneously)
            const float* hT = h1s + (size_t)T_STEPS*HP;
            const bool hi = (c1 + 4 <= H);
            v4f ha, hb;
            for (;;) {
                poll2(hT + c0, hT + c1, ha, hb);
                bool ok = nz4(ha) && (!hi || nz4(hb));
                if (__all(ok)) break;
            }
            v4f v0 = v4sub(ha, BIAS2);
            v4f v1 = hi ? v4sub(hb, BIAS2) : v4z();
            #pragma unroll 4
            for (int r = 0; r < NCLS; ++r) {
                const float* wr = fcW + (size_t)r*H;
                v4f wa = *(const v4f*)(wr + c0);
                v4f wb = hi ? *(const v4f*)(wr + c1) : v4z();
                float a = dot4(wa, v0) + dot4(wb, v1);
                #pragma unroll
                for (int m = 32; m >= 1; m >>= 1) a += __shfl_xor(a, m, 64);
                if (j == 0) out[r] = a + fcb[r];
            }
        }
    }
}

extern "C" void kernel_launch(void* const* d_in, const int* in_sizes, int n_in,
                              void* d_out, int out_size, void* d_ws, size_t ws_size,
                              hipStream_t stream)
{
    const int*   seq  = (const int*)d_in[0];
    const float* emb  = (const float*)d_in[1];
    const float* Wih0 = (const float*)d_in[2];
    const float* Whh0 = (const float*)d_in[3];
    const float* bih0 = (const float*)d_in[4];
    const float* bhh0 = (const float*)d_in[5];
    const float* Wih1 = (const float*)d_in[6];
    const float* Whh1 = (const float*)d_in[7];
    const float* bih1 = (const float*)d_in[8];
    const float* bhh1 = (const float*)d_in[9];
    const float* fcW  = (const float*)d_in[10];
    const float* fcb  = (const float*)d_in[11];
    float* out = (float*)d_out;

    float* h0s = (float*)d_ws;
    float* h1s = h0s + (size_t)(T_STEPS+1)*HP;

    // zero/seed both h buffers: 2*2049*512 floats = 524544 float4 = 2049 blocks * 256 thr
    hipLaunchKernelGGL(lstm_init, dim3(2049), dim3(256), 0, stream, h0s);
    hipLaunchKernelGGL(lstm_main, dim3(2*NW), dim3(64), 0, stream,
                       seq, emb, Wih0, Whh0, bih0, bhh0, Wih1, Whh1, bih1, bhh1,
                       fcW, fcb, out, h0s, h1s);
}

// Round 5
// 5895.977 us; speedup vs baseline: 2.7462x; 1.9817x over previous
//
#include <hip/hip_runtime.h>

#define T_STEPS 2048
#define H       500
#define E       300
#define HP      512      // padded h stride (floats)
#define XPT     2048     // xproj t-stride
#define NCLS    20
#define NB0     125      // L0 blocks (4 units each)
#define NB1     125      // L1 blocks (4 units each, 2 waves)
#define BIAS2   2.0f

typedef float v4f __attribute__((ext_vector_type(4)));

__device__ __forceinline__ float sigm_(float x){ return 1.0f/(1.0f+__expf(-x)); }
__device__ __forceinline__ float tanh_(float x){ return 2.0f/(1.0f+__expf(-2.0f*x)) - 1.0f; }

__device__ __forceinline__ v4f v4z() { v4f r; r.x=0.f; r.y=0.f; r.z=0.f; r.w=0.f; return r; }
__device__ __forceinline__ v4f v4sub(v4f v, float s){ v4f r; r.x=v.x-s; r.y=v.y-s; r.z=v.z-s; r.w=v.w-s; return r; }
__device__ __forceinline__ bool nz4(v4f v){ return v.x!=0.f && v.y!=0.f && v.z!=0.f && v.w!=0.f; }
__device__ __forceinline__ float dot4(v4f w, v4f x){ return w.x*x.x + w.y*x.y + w.z*x.z + w.w*x.w; }

// device-coherent poll loads (bypass L1/L2, served by LLC). NO memory clobber:
// consumed data flows through outputs; volatile keeps program order vs stores.
__device__ __forceinline__ void poll2(const float* p0, const float* p1, v4f& a, v4f& b) {
    asm volatile("global_load_dwordx4 %0, %2, off sc0 sc1\n\t"
                 "global_load_dwordx4 %1, %3, off sc0 sc1\n\t"
                 "s_waitcnt vmcnt(0)"
                 : "=&v"(a), "=&v"(b)
                 : "v"(p0), "v"(p1));
}
__device__ __forceinline__ void store1_cc(float* p, float v) {
    asm volatile("global_store_dword %0, %1, off sc0 sc1" :: "v"(p), "v"(v));
}

// h buffers t-indexed; 0 == not written (real values are h+2 in (1,3)).
__global__ __launch_bounds__(256) void lstm_init(float* hs) {
    int i = blockIdx.x*256 + threadIdx.x;
    const int NH4 = (T_STEPS+1)*HP/4;
    v4f b2; b2.x=BIAS2; b2.y=BIAS2; b2.z=BIAS2; b2.w=BIAS2;
    bool seed = (i < H/4) || (i >= NH4 && i < NH4 + H/4);
    ((v4f*)hs)[i] = seed ? b2 : v4z();
}

// xproj[row][t] = W_ih0[row,:] . emb[seq[t],:] + bih0[row] + bhh0[row]
__global__ __launch_bounds__(256) void xproj_kernel(
    const int* __restrict__ seq, const float* __restrict__ emb,
    const float* __restrict__ Wih0, const float* __restrict__ bih0,
    const float* __restrict__ bhh0, float* __restrict__ xp)
{
    __shared__ float xe[16][308];            // padded: 2-way max bank conflict
    const int tid = threadIdx.x;
    const int t0 = blockIdx.x * 16;
    for (int i = tid; i < 16*76; i += 256) {
        int tt = i / 76, c4 = (i - tt*76) * 4;
        v4f val = v4z();
        if (c4 < E) val = *(const v4f*)&emb[(size_t)seq[t0+tt]*E + c4];   // 300%4==0
        *(v4f*)&xe[tt][c4] = val;
    }
    __syncthreads();
    const int rg = tid >> 4, tl = tid & 15;
    for (int k = 0; k < 125; ++k) {
        int row = k*16 + rg;
        const float* wr = Wih0 + (size_t)row*E;
        float acc = bih0[row] + bhh0[row];
        #pragma unroll 5
        for (int c = 0; c < 75; ++c)
            acc += dot4(*(const v4f*)(wr + 4*c), *(const v4f*)&xe[tl][4*c]);
        xp[(size_t)row*XPT + t0 + tl] = acc;
    }
}

// reduce-scatter: acc[16] logical gate-rows summed over 64 lanes.
// Result: lane L holds total of row r(L) = 8*b0 + 4*b1 + 2*b2 + b3 (bits of L).
__device__ __forceinline__ float reduce16(float* acc, int lane) {
    float v8[8];
    {
        const bool b = lane & 1;
        #pragma unroll
        for (int i = 0; i < 8; ++i) {
            float keep = b ? acc[8+i] : acc[i];
            float send = b ? acc[i]   : acc[8+i];
            v8[i] = keep + __shfl_xor(send, 1, 64);
        }
    }
    float v4a[4];
    {
        const bool b = lane & 2;
        #pragma unroll
        for (int i = 0; i < 4; ++i) {
            float keep = b ? v8[4+i] : v8[i];
            float send = b ? v8[i]   : v8[4+i];
            v4a[i] = keep + __shfl_xor(send, 2, 64);
        }
    }
    float v2a[2];
    {
        const bool b = lane & 4;
        #pragma unroll
        for (int i = 0; i < 2; ++i) {
            float keep = b ? v4a[2+i] : v4a[i];
            float send = b ? v4a[i]   : v4a[2+i];
            v2a[i] = keep + __shfl_xor(send, 4, 64);
        }
    }
    float v1;
    {
        const bool b = lane & 8;
        float keep = b ? v2a[1] : v2a[0];
        float send = b ? v2a[0] : v2a[1];
        v1 = keep + __shfl_xor(send, 8, 64);
    }
    v1 += __shfl_xor(v1, 16, 64);
    v1 += __shfl_xor(v1, 32, 64);
    return v1;
}

// x = pre-activation of this lane's gate-row; returns h of this lane's unit.
__device__ __forceinline__ float gates_combine(float x, int b2, int b3, float& cs) {
    const bool isG = (b2 == 1 && b3 == 0);                 // gate==2 (tanh)
    float a = 1.f/(1.f + __expf(isG ? -2.f*x : -x));       // tanh(x)=2*sigm(2x)-1
    float act = isG ? 2.f*a - 1.f : a;
    float t1 = __shfl_xor(act, 4, 64);                     // flip b2
    float t2 = __shfl_xor(act, 8, 64);                     // flip b3
    float t3 = __shfl_xor(act, 12, 64);                    // flip both
    float gi = b2 ? (b3 ? t3 : t1) : (b3 ? t2 : act);
    float gf = b2 ? (b3 ? t1 : t3) : (b3 ? act : t2);
    float gg = b2 ? (b3 ? t2 : act) : (b3 ? t3 : t1);
    float go = b2 ? (b3 ? act : t2) : (b3 ? t1 : t3);
    cs = gf*cs + gi*gg;
    return go * tanh_(cs);
}

__launch_bounds__(128, 1)
__global__ void lstm_main(
    const float* __restrict__ Whh0,
    const float* __restrict__ Wih1, const float* __restrict__ Whh1,
    const float* __restrict__ bih1, const float* __restrict__ bhh1,
    const float* __restrict__ fcW, const float* __restrict__ fcb,
    float* __restrict__ out,
    const float* __restrict__ xp, float* h0s, float* h1s)
{
    __shared__ float part[2][64];
    const int blk  = blockIdx.x;
    const int wid  = threadIdx.x >> 6;
    const int lane = threadIdx.x & 63;
    const int c0 = 8*lane;
    const bool need0 = (c0 + 4 <= H);
    const bool need1 = (c0 + 8 <= H);
    const int b0 = lane&1, b1=(lane>>1)&1, b2=(lane>>2)&1, b3=(lane>>3)&1;
    const int unit = 2*b0 + b1;                  // r(L)>>2
    const int gate = 2*b2 + b3;                  // r(L)&3

    if (blk < NB0) {
        // ===================== layer 0 (single wave) =====================
        if (wid == 1) return;                    // no barriers in this path
        const int u0 = 4*blk;
        v4f w[16][2];
        #pragma unroll
        for (int r = 0; r < 16; ++r) {
            const int R_ = (r&3)*H + u0 + (r>>2);
            const float* wh = Whh0 + (size_t)R_*H;
            w[r][0] = need0 ? *(const v4f*)(wh + c0)     : v4z();
            w[r][1] = need1 ? *(const v4f*)(wh + c0 + 4) : v4z();
        }
        const float* xpp = xp + (size_t)(gate*H + u0 + unit)*XPT;  // this lane's row
        float cs = 0.f;

        for (int t = 1; t <= T_STEPS; ++t) {
            float xpv = xpp[t-1];
            const float* hp = h0s + (size_t)(t-1)*HP;
            v4f A = v4z(), B = v4z();
            bool ok = !(need0 || need1);
            while (!__all(ok)) {
                if (!ok) {
                    poll2(hp + c0, hp + c0 + 4, A, B);
                    ok = (!need0 || nz4(A)) && (!need1 || nz4(B));
                }
            }
            v4f i0 = v4sub(A, BIAS2), i1 = v4sub(B, BIAS2);
            float acc[16];
            #pragma unroll
            for (int r = 0; r < 16; ++r)
                acc[r] = dot4(w[r][0], i0) + dot4(w[r][1], i1);
            float v = reduce16(acc, lane);
            float hval = gates_combine(v + xpv, b2, b3, cs);
            if ((lane & 60) == 0)
                store1_cc(h0s + (size_t)t*HP + u0 + unit, hval + BIAS2);
        }
    } else {
        // ===================== layer 1 (two waves) =====================
        const int g  = blk - NB0;
        const int u0 = 4*g;
        if (wid == 0) {
            // wave0: W_ih1 . h0(t) part + combine + gates + store
            v4f w[16][2];
            float bsum;
            {
                const int R_ = gate*H + u0 + unit;
                bsum = bih1[R_] + bhh1[R_];
            }
            #pragma unroll
            for (int r = 0; r < 16; ++r) {
                const int R_ = (r&3)*H + u0 + (r>>2);
                const float* wi = Wih1 + (size_t)R_*H;
                w[r][0] = need0 ? *(const v4f*)(wi + c0)     : v4z();
                w[r][1] = need1 ? *(const v4f*)(wi + c0 + 4) : v4z();
            }
            float cs = 0.f;
            for (int t = 1; t <= T_STEPS; ++t) {
                const float* hp = h0s + (size_t)t*HP;
                v4f A = v4z(), B = v4z();
                bool ok = !(need0 || need1);
                while (!__all(ok)) {
                    if (!ok) {
                        poll2(hp + c0, hp + c0 + 4, A, B);
                        ok = (!need0 || nz4(A)) && (!need1 || nz4(B));
                    }
                }
                v4f i0 = v4sub(A, BIAS2), i1 = v4sub(B, BIAS2);
                float acc[16];
                #pragma unroll
                for (int r = 0; r < 16; ++r)
                    acc[r] = dot4(w[r][0], i0) + dot4(w[r][1], i1);
                float v = reduce16(acc, lane);
                __syncthreads();
                v += part[t&1][lane];
                float hval = gates_combine(v + bsum, b2, b3, cs);
                if ((lane & 60) == 0)
                    store1_cc(h1s + (size_t)t*HP + u0 + unit, hval + BIAS2);
            }
            if (g == 0) {
                // final FC on h1[T]
                const float* hT = h1s + (size_t)T_STEPS*HP;
                v4f A = v4z(), B = v4z();
                bool ok = !(need0 || need1);
                while (!__all(ok)) {
                    if (!ok) {
                        poll2(hT + c0, hT + c0 + 4, A, B);
                        ok = (!need0 || nz4(A)) && (!need1 || nz4(B));
                    }
                }
                v4f h0v = need0 ? v4sub(A, BIAS2) : v4z();
                v4f h1v = need1 ? v4sub(B, BIAS2) : v4z();
                #pragma unroll 4
                for (int r = 0; r < NCLS; ++r) {
                    const float* wr = fcW + (size_t)r*H;
                    v4f wa = need0 ? *(const v4f*)(wr + c0)     : v4z();
                    v4f wb = need1 ? *(const v4f*)(wr + c0 + 4) : v4z();
                    float a = dot4(wa, h0v) + dot4(wb, h1v);
                    #pragma unroll
                    for (int m = 32; m >= 1; m >>= 1) a += __shfl_xor(a, m, 64);
                    if (lane == 0) out[r] = a + fcb[r];
                }
            }
        } else {
            // wave1: W_hh1 . h1(t-1) partials -> LDS
            v4f w[16][2];
            #pragma unroll
            for (int r = 0; r < 16; ++r) {
                const int R_ = (r&3)*H + u0 + (r>>2);
                const float* wh = Whh1 + (size_t)R_*H;
                w[r][0] = need0 ? *(const v4f*)(wh + c0)     : v4z();
                w[r][1] = need1 ? *(const v4f*)(wh + c0 + 4) : v4z();
            }
            for (int t = 1; t <= T_STEPS; ++t) {
                const float* hp = h1s + (size_t)(t-1)*HP;
                v4f A = v4z(), B = v4z();
                bool ok = !(need0 || need1);
                while (!__all(ok)) {
                    if (!ok) {
                        poll2(hp + c0, hp + c0 + 4, A, B);
                        ok = (!need0 || nz4(A)) && (!need1 || nz4(B));
                    }
                }
                v4f i0 = v4sub(A, BIAS2), i1 = v4sub(B, BIAS2);
                float acc[16];
                #pragma unroll
                for (int r = 0; r < 16; ++r)
                    acc[r] = dot4(w[r][0], i0) + dot4(w[r][1], i1);
                part[t&1][lane] = reduce16(acc, lane);
                __syncthreads();
            }
        }
    }
}

extern "C" void kernel_launch(void* const* d_in, const int* in_sizes, int n_in,
                              void* d_out, int out_size, void* d_ws, size_t ws_size,
                              hipStream_t stream)
{
    const int*   seq  = (const int*)d_in[0];
    const float* emb  = (const float*)d_in[1];
    const float* Whh0 = (const float*)d_in[3];
    const float* bih0 = (const float*)d_in[4];
    const float* bhh0 = (const float*)d_in[5];
    const float* Wih0 = (const float*)d_in[2];
    const float* Wih1 = (const float*)d_in[6];
    const float* Whh1 = (const float*)d_in[7];
    const float* bih1 = (const float*)d_in[8];
    const float* bhh1 = (const float*)d_in[9];
    const float* fcW  = (const float*)d_in[10];
    const float* fcb  = (const float*)d_in[11];
    float* out = (float*)d_out;

    float* h0s = (float*)d_ws;
    float* h1s = h0s + (size_t)(T_STEPS+1)*HP;
    float* xpj = h1s + (size_t)(T_STEPS+1)*HP;   // 4*H rows x XPT floats (16.4 MB)

    hipLaunchKernelGGL(lstm_init, dim3(2049), dim3(256), 0, stream, h0s);
    hipLaunchKernelGGL(xproj_kernel, dim3(T_STEPS/16), dim3(256), 0, stream,
                       seq, emb, Wih0, bih0, bhh0, xpj);
    hipLaunchKernelGGL(lstm_main, dim3(NB0 + NB1), dim3(128), 0, stream,
                       Whh0, Wih1, Whh1, bih1, bhh1, fcW, fcb, out, xpj, h0s, h1s);
}